// Round 1
// baseline (147.355 us; speedup 1.0000x reference)
//
#include <hip/hip_runtime.h>

// 4096-point FFT = three radix-16 stages, per (b,h) row, one block per row.
// LDS row stride 272 (=256+16 pad) keeps every b32 access <=2-way bank aliased.
#define RS    272
#define PLANE 4352   // 16*RS

__device__ __forceinline__ void cmat16(const float* __restrict__ M,
                                       const float ar[16], const float ai[16],
                                       float yr[16], float yi[16])
{
    // y[j] = sum_o M[j][o] * a[o]  (complex), M rows are (re,im) interleaved.
    // M is block-uniform (indexed only by h and compile-time j,o) -> s_loads.
#pragma unroll
    for (int j = 0; j < 16; ++j) {
        float sr = 0.f, si = 0.f;
#pragma unroll
        for (int o = 0; o < 16; ++o) {
            const float mr = M[j * 32 + 2 * o];
            const float mi = M[j * 32 + 2 * o + 1];
            sr = fmaf(mr, ar[o], sr);
            sr = fmaf(-mi, ai[o], sr);
            si = fmaf(mr, ai[o], si);
            si = fmaf(mi, ar[o], si);
        }
        yr[j] = sr;
        yi[j] = si;
    }
}

__global__ __launch_bounds__(256) void fft4096_kernel(
    const float* __restrict__ xre, const float* __restrict__ xim,
    const float* __restrict__ mat16, float* __restrict__ out, int H)
{
    __shared__ float Sre[PLANE];
    __shared__ float Sim[PLANE];

    const int    t    = threadIdx.x;            // 0..255
    const int    bh   = blockIdx.x;             // b*H + h
    const int    h    = bh % H;
    const size_t base = (size_t)bh * 4096;
    const float* __restrict__ M = mat16 + (size_t)h * 512;

    float ar[16], ai[16], yr[16], yi[16];

    // ---------------- stage 1: DFT-16 along o (stride 256), n1 = t ----------
#pragma unroll
    for (int o = 0; o < 16; ++o) {
        ar[o] = xre[base + (size_t)(o * 256 + t)];
        ai[o] = xim[base + (size_t)(o * 256 + t)];
    }
    cmat16(M, ar, ai, yr, yi);
    {
        // tw4096(t*m) = w^m, w = exp(-2*pi*i*t/4096)
        const float a = -1.5339807878856412e-03f * (float)t;
        float ws, wc;
        sincosf(a, &ws, &wc);
        float cr = 1.f, ci = 0.f;
#pragma unroll
        for (int m = 0; m < 16; ++m) {
            Sre[m * RS + t] = yr[m] * cr - yi[m] * ci;
            Sim[m * RS + t] = yr[m] * ci + yi[m] * cr;
            const float ncr = cr * wc - ci * ws;
            const float nci = cr * ws + ci * wc;
            cr = ncr; ci = nci;
        }
    }
    __syncthreads();

    // ---------------- stage 2: thread = (m1 = t>>4, n2 = t&15) --------------
    const int m1 = t >> 4, n2 = t & 15;
#pragma unroll
    for (int o = 0; o < 16; ++o) {
        ar[o] = Sre[m1 * RS + o * 16 + n2];
        ai[o] = Sim[m1 * RS + o * 16 + n2];
    }
    __syncthreads();   // all reads done before in-place overwrite
    cmat16(M, ar, ai, yr, yi);
    {
        // tw256(n2*m2') = w2^m2', w2 = exp(-2*pi*i*n2/256)
        const float a = -2.454369260617026e-02f * (float)n2;
        float ws, wc;
        sincosf(a, &ws, &wc);
        float cr = 1.f, ci = 0.f;
#pragma unroll
        for (int j = 0; j < 16; ++j) {
            const int p = n2 * RS + j * 16 + (m1 ^ n2);   // XOR swizzle
            Sre[p] = yr[j] * cr - yi[j] * ci;
            Sim[p] = yr[j] * ci + yi[j] * cr;
            const float ncr = cr * wc - ci * ws;
            const float nci = cr * ws + ci * wc;
            cr = ncr; ci = nci;
        }
    }
    __syncthreads();

    // ---------------- stage 3: thread = (m2p = t>>4, m = t&15) --------------
    const int m = t & 15, m2p = t >> 4;
#pragma unroll
    for (int o = 0; o < 16; ++o) {
        ar[o] = Sre[o * RS + m2p * 16 + (m ^ o)];
        ai[o] = Sim[o * RS + m2p * 16 + (m ^ o)];
    }
    cmat16(M, ar, ai, yr, yi);

    // out index k = j*256 + m2p*16 + m = j*256 + t  -> contiguous float2
    float2* __restrict__ o2 = (float2*)out;
#pragma unroll
    for (int j = 0; j < 16; ++j) {
        o2[base + (size_t)(j * 256 + t)] = make_float2(yr[j], yi[j]);
    }
}

extern "C" void kernel_launch(void* const* d_in, const int* in_sizes, int n_in,
                              void* d_out, int out_size, void* d_ws, size_t ws_size,
                              hipStream_t stream)
{
    const float* xre = (const float*)d_in[0];
    const float* xim = (const float*)d_in[1];
    const float* m16 = (const float*)d_in[5];   // (H,16,16,2) fp32
    const int H  = in_sizes[5] / 512;           // 16*16*2
    const int BH = in_sizes[0] / 4096;          // B*H rows
    fft4096_kernel<<<dim3(BH), dim3(256), 0, stream>>>(
        xre, xim, m16, (float*)d_out, H);
}

// Round 3
// 48.253 us; speedup vs baseline: 3.0538x; 3.0538x over previous
//
#include <hip/hip_runtime.h>
#include <stdint.h>

typedef _Float16 f16x8 __attribute__((ext_vector_type(8)));
typedef float    f32x4 __attribute__((ext_vector_type(4)));

union FragU { unsigned u[4]; f16x8 h; };

__device__ __forceinline__ unsigned pkh(float a, float b) {
    return __builtin_bit_cast(unsigned, __builtin_amdgcn_cvt_pkrtz(a, b));
}

#define MFMA(A, B, C) __builtin_amdgcn_mfma_f32_16x16x32_f16((A).h, (B).h, (C), 0, 0, 0)

#define K1 (-1.5339807878856412e-03f)   /* -2*pi/4096 */
#define K2 (-2.4543692606170259e-02f)   /* -2*pi/256  */

// 4096-pt FFT = 3 radix-16 stages; each stage = complex 16x16 GEMM via
// mfma_f32_16x16x32_f16 with K=32 stacking: Yr=[Mr|Mi]*[Xr;-Xi], Yi=[Mr|Mi]*[Xi;Xr].
// One block per (b,h) row; 4 waves, each owning 4 MFMA tiles per stage.
__global__ __launch_bounds__(256) void fft4096_mfma(
    const float* __restrict__ xre, const float* __restrict__ xim,
    const float* __restrict__ mat16, float* __restrict__ out, int H)
{
    // bytes: LDS1 re @0, im @8192 ; LDS2 re @16384, im @24576 ; F overlays all.
    __shared__ __align__(16) unsigned char smem[33024];

    const int t = threadIdx.x;
    const int w = t >> 6;          // wave 0..3
    const int l = t & 63;
    const int g = l >> 4;          // lane group 0..3
    const int c = l & 15;          // lane col 0..15
    const int bh = blockIdx.x;
    const int h  = bh % H;
    const size_t base = (size_t)bh * 4096;

    // ---- M fragments (one load, reused by all 3 stages) ----
    // lane: row=c, o-block=g -> M[h][c][4g..4g+3][re,im]  (8 contiguous floats)
    const float* Mb = mat16 + (size_t)h * 512 + (size_t)c * 32 + g * 8;
    const float4 mf0 = *(const float4*)Mb;
    const float4 mf1 = *(const float4*)(Mb + 4);
    const unsigned mrA = pkh(mf0.x, mf0.z), mrB = pkh(mf1.x, mf1.z);
    const unsigned miA = pkh(mf0.y, mf0.w), miB = pkh(mf1.y, mf1.w);
    const unsigned nmiA = miA ^ 0x80008000u, nmiB = miB ^ 0x80008000u;

    FragU Afrag;  // A = [Mr | Mi] (stages 1,2)
    Afrag.u[0] = mrA; Afrag.u[1] = mrB; Afrag.u[2] = miA; Afrag.u[3] = miB;
    FragU BMr;    // stage3 B for Vr^T: [Mr^T ; -Mi^T]
    BMr.u[0] = mrA; BMr.u[1] = mrB; BMr.u[2] = nmiA; BMr.u[3] = nmiB;
    FragU BMi;    // stage3 B for Vi^T: [Mi^T ; Mr^T]
    BMi.u[0] = miA; BMi.u[1] = miB; BMi.u[2] = mrA; BMi.u[3] = mrB;

    const f32x4 zero = {0.f, 0.f, 0.f, 0.f};

    // ================= stage 1: Y1[m1][j] = sum_o M[m1][o] x[o*256+j] =========
    f32x4 s1r[4], s1i[4];
#pragma unroll
    for (int p = 0; p < 4; ++p) {
        const int col = (4 * w + p) * 16 + c;      // j within row
        float xr[4], xi[4];
#pragma unroll
        for (int jj = 0; jj < 4; ++jj) {           // k = o = 4g+jj
            xr[jj] = xre[base + (size_t)((4 * g + jj) * 256 + col)];
            xi[jj] = xim[base + (size_t)((4 * g + jj) * 256 + col)];
        }
        const unsigned rp0 = pkh(xr[0], xr[1]), rp1 = pkh(xr[2], xr[3]);
        const unsigned ip0 = pkh(xi[0], xi[1]), ip1 = pkh(xi[2], xi[3]);
        const unsigned np0 = pkh(-xi[0], -xi[1]), np1 = pkh(-xi[2], -xi[3]);
        FragU Br; Br.u[0] = rp0; Br.u[1] = rp1; Br.u[2] = np0; Br.u[3] = np1;
        FragU Bi; Bi.u[0] = ip0; Bi.u[1] = ip1; Bi.u[2] = rp0; Bi.u[3] = rp1;
        s1r[p] = MFMA(Afrag, Br, zero);
        s1i[p] = MFMA(Afrag, Bi, zero);
    }
    // twiddle tw4096(j*m1), m1 = 4g+reg (D rows), applied in place
#pragma unroll
    for (int p = 0; p < 4; ++p) {
        const int j = (4 * w + p) * 16 + c;
        float sb, cb, ss, cs;
        __sincosf(K1 * (float)(j * 4 * g), &sb, &cb);   // base: m1 = 4g
        __sincosf(K1 * (float)j, &ss, &cs);             // step per reg
#pragma unroll
        for (int reg = 0; reg < 4; ++reg) {
            const float yr = s1r[p][reg], yi = s1i[p][reg];
            s1r[p][reg] = yr * cb - yi * sb;
            s1i[p][reg] = yr * sb + yi * cb;
            const float nc = cb * cs - sb * ss;
            const float ns = cb * ss + sb * cs;
            cb = nc; sb = ns;
        }
    }
    // LDS1 [m1][o3][o2] halves, o2-block XOR-swizzled: s=(o2>>2)^(o3>>2)^(m1&3)
#pragma unroll
    for (int reg = 0; reg < 4; ++reg) {
        const int m1 = 4 * g + reg;
        const int half = m1 * 256 + c * 16 + 4 * ((w ^ (c >> 2) ^ reg) & 3);
        uint2 vr, vi;
        vr.x = pkh(s1r[0][reg], s1r[1][reg]); vr.y = pkh(s1r[2][reg], s1r[3][reg]);
        vi.x = pkh(s1i[0][reg], s1i[1][reg]); vi.y = pkh(s1i[2][reg], s1i[3][reg]);
        *(uint2*)(smem + half * 2)        = vr;
        *(uint2*)(smem + 8192 + half * 2) = vi;
    }
    __syncthreads();

    // ================= stage 2: A2[m2][o3] = sum_o2 M[m2][o2] T[o2*16+o3] =====
    f32x4 s2r[4], s2i[4];
#pragma unroll
    for (int p = 0; p < 4; ++p) {
        const int m1 = 4 * w + p;                  // tile = m1
        const int half = m1 * 256 + c * 16 + 4 * ((g ^ (c >> 2) ^ p) & 3);
        const uint2 rp = *(const uint2*)(smem + half * 2);
        const uint2 ip = *(const uint2*)(smem + 8192 + half * 2);
        FragU Br; Br.u[0] = rp.x; Br.u[1] = rp.y;
        Br.u[2] = ip.x ^ 0x80008000u; Br.u[3] = ip.y ^ 0x80008000u;
        FragU Bi; Bi.u[0] = ip.x; Bi.u[1] = ip.y; Bi.u[2] = rp.x; Bi.u[3] = rp.y;
        s2r[p] = MFMA(Afrag, Br, zero);
        s2i[p] = MFMA(Afrag, Bi, zero);
    }
    // tw256(o3*m2): o3=c, m2=4g+reg (same for all tiles)
    float twc[4], tws[4];
    {
        float sb, cb, ss, cs;
        __sincosf(K2 * (float)(c * 4 * g), &sb, &cb);
        __sincosf(K2 * (float)c, &ss, &cs);
#pragma unroll
        for (int reg = 0; reg < 4; ++reg) {
            twc[reg] = cb; tws[reg] = sb;
            const float nc = cb * cs - sb * ss;
            const float ns = cb * ss + sb * cs;
            cb = nc; sb = ns;
        }
    }
#pragma unroll
    for (int p = 0; p < 4; ++p) {
#pragma unroll
        for (int reg = 0; reg < 4; ++reg) {
            const float yr = s2r[p][reg], yi = s2i[p][reg];
            s2r[p][reg] = yr * twc[reg] - yi * tws[reg];
            s2i[p][reg] = yr * tws[reg] + yi * twc[reg];
        }
    }
    // LDS2 [m2][o3][m1] halves, m1-block swizzle s=(m1>>2)^(o3>>2)^(m2&3)
#pragma unroll
    for (int reg = 0; reg < 4; ++reg) {
        const int m2 = 4 * g + reg;
        const int half = m2 * 256 + c * 16 + 4 * ((w ^ (c >> 2) ^ reg) & 3);
        uint2 vr, vi;
        vr.x = pkh(s2r[0][reg], s2r[1][reg]); vr.y = pkh(s2r[2][reg], s2r[3][reg]);
        vi.x = pkh(s2i[0][reg], s2i[1][reg]); vi.y = pkh(s2i[2][reg], s2i[3][reg]);
        *(uint2*)(smem + 16384 + half * 2) = vr;
        *(uint2*)(smem + 24576 + half * 2) = vi;
    }
    __syncthreads();

    // ================= stage 3: V^T[m2][n3] = sum_o3 U^T[m2][o3] M^T[o3][n3] ==
    // A = [Ur^T | Ui^T]: lane row = m2 = c, k = o3 = 4g+jj, tile = m1 = 4w+p
    FragU Aup[4];
#pragma unroll
    for (int p = 0; p < 4; ++p) {
        unsigned short hr[4], hi[4];
#pragma unroll
        for (int jj = 0; jj < 4; ++jj) {
            const int o3 = 4 * g + jj;
            const int half = c * 256 + o3 * 16 + 4 * ((w ^ g ^ (c & 3)) & 3) + p;
            hr[jj] = *(const unsigned short*)(smem + 16384 + half * 2);
            hi[jj] = *(const unsigned short*)(smem + 24576 + half * 2);
        }
        Aup[p].u[0] = (unsigned)hr[0] | ((unsigned)hr[1] << 16);
        Aup[p].u[1] = (unsigned)hr[2] | ((unsigned)hr[3] << 16);
        Aup[p].u[2] = (unsigned)hi[0] | ((unsigned)hi[1] << 16);
        Aup[p].u[3] = (unsigned)hi[2] | ((unsigned)hi[3] << 16);
    }
    __syncthreads();   // all LDS2 reads done before F overlays it

    f32x4 vR[4], vI[4];
#pragma unroll
    for (int p = 0; p < 4; ++p) {
        vR[p] = MFMA(Aup[p], BMr, zero);
        vI[p] = MFMA(Aup[p], BMi, zero);
    }
    // F[n3][m2][m1] float2 (row stride 258), = out[n3*256 + m2*16 + m1]
#pragma unroll
    for (int reg = 0; reg < 4; ++reg) {
        const int fidx = c * 258 + (4 * g + reg) * 16 + 4 * w;
        float4 a, b;
        a.x = vR[0][reg]; a.y = vI[0][reg]; a.z = vR[1][reg]; a.w = vI[1][reg];
        b.x = vR[2][reg]; b.y = vI[2][reg]; b.z = vR[3][reg]; b.w = vI[3][reg];
        *(float4*)(smem + (size_t)fidx * 8)      = a;
        *(float4*)(smem + (size_t)fidx * 8 + 16) = b;
    }
    __syncthreads();

    // coalesced final store
    float2* __restrict__ og = (float2*)out;
#pragma unroll
    for (int jr = 0; jr < 16; ++jr) {
        const float2 v = *(const float2*)(smem + (size_t)(jr * 258 + t) * 8);
        og[base + (size_t)(jr * 256 + t)] = v;
    }
}

extern "C" void kernel_launch(void* const* d_in, const int* in_sizes, int n_in,
                              void* d_out, int out_size, void* d_ws, size_t ws_size,
                              hipStream_t stream)
{
    const float* xre = (const float*)d_in[0];
    const float* xim = (const float*)d_in[1];
    const float* m16 = (const float*)d_in[5];   // (H,16,16,2) fp32
    const int H  = in_sizes[5] / 512;
    const int BH = in_sizes[0] / 4096;
    fft4096_mfma<<<dim3(BH), dim3(256), 0, stream>>>(
        xre, xim, m16, (float*)d_out, H);
}